// Round 5
// baseline (337.221 us; speedup 1.0000x reference)
//
#include <hip/hip_runtime.h>
#include <hip/hip_bf16.h>

#define LLSZ 65536  // L*L
#define INV_LL (1.f / 65536.f)

// B=2, L=256, SD=64, PD=32, H=4, HD=16, OH=32, EXP=64, SE=16

__device__ __forceinline__ void chan_stats(const float* sum, const float* sumsq,
                                           int chan, float& m, float& isd)
{
    m = sum[chan] * INV_LL;
    float var = sumsq[chan] * INV_LL - m * m;
    isd = rsqrtf(var + 1e-5f);
}

__device__ __forceinline__ float silu(float t) { return t / (1.f + expf(-t)); }

// ---------- kA: block 0 = {zero stats, G/GW/BW prep}; blocks 1..128 = seq LN -> a, qkv ----------
__global__ __launch_bounds__(256) void kA(
    const float* __restrict__ g_opm, const float* __restrict__ b_opm,
    const float* __restrict__ Wproj, const float* __restrict__ b_proj,
    float* __restrict__ G, float* __restrict__ GW, float* __restrict__ BW,
    float* __restrict__ stats0,   // 768 floats to zero
    const float* __restrict__ seq, const float* __restrict__ g_attn,
    const float* __restrict__ b_attn, const float* __restrict__ W_lin,
    const float* __restrict__ b_lin, const float* __restrict__ W_qkv,
    float* __restrict__ a, float* __restrict__ am, float* __restrict__ s2,
    float* __restrict__ qkv)
{
    int tid = threadIdx.x;
    if (blockIdx.x == 0) {
        for (int k = tid; k < 768; k += 256) stats0[k] = 0.f;
        int p = tid & 31, rg = tid >> 5;  // rg 0..7
        float gw = 0.f, bw = 0.f;
        #pragma unroll 8
        for (int k = 0; k < 128; ++k) {
            int de = k * 8 + rg;
            float wv = Wproj[de * 32 + p];
            float gv = g_opm[de] * wv;
            G[de * 32 + p] = gv;
            gw += gv;
            bw += b_opm[de] * wv;
        }
        __shared__ float rG[256], rB[256];
        rG[rg * 32 + p] = gw;
        rB[rg * 32 + p] = bw;
        __syncthreads();
        for (int s = 4; s > 0; s >>= 1) {
            if (rg < s) {
                rG[rg * 32 + p] += rG[(rg + s) * 32 + p];
                rB[rg * 32 + p] += rB[(rg + s) * 32 + p];
            }
            __syncthreads();
        }
        if (tid < 32) { GW[p] = rG[p]; BW[p] = rB[p] + b_proj[p]; }
    } else {
        __shared__ float Wq[64 * 192];
        __shared__ float Wl[64 * 32];
        __shared__ float xL[4][64];
        #pragma unroll
        for (int k = 0; k < 48; ++k) Wq[k * 256 + tid] = W_qkv[k * 256 + tid];
        #pragma unroll
        for (int k = 0; k < 8; ++k) Wl[k * 256 + tid] = W_lin[k * 256 + tid];
        int sub = tid >> 6, t = tid & 63;
        int row = (blockIdx.x - 1) * 4 + sub;
        float v = seq[row * 64 + t];
        float m = v;
        for (int k = 32; k > 0; k >>= 1) m += __shfl_xor(m, k, 64);
        m *= (1.f / 64.f);
        float d = v - m;
        float var = d * d;
        for (int k = 32; k > 0; k >>= 1) var += __shfl_xor(var, k, 64);
        var *= (1.f / 64.f);
        float x = d * rsqrtf(var + 1e-5f) * g_attn[t] + b_attn[t];
        xL[sub][t] = x;
        __syncthreads();
        if (t < 32) {
            float s = 0.f;
            #pragma unroll
            for (int dd = 0; dd < 64; ++dd) s += xL[sub][dd] * Wl[dd * 32 + t];
            s += b_lin[t];
            a[row * 32 + t] = s;
            float mm = s, ss = s * s;
            for (int k = 16; k > 0; k >>= 1) {
                mm += __shfl_xor(mm, k, 32);
                ss += __shfl_xor(ss, k, 32);
            }
            if (t == 0) { am[row] = mm * (1.f / 32.f); s2[row] = ss * (1.f / 32.f); }
        }
        #pragma unroll
        for (int c3 = 0; c3 < 3; ++c3) {
            int c = c3 * 64 + t;
            float s = 0.f;
            #pragma unroll
            for (int dd = 0; dd < 64; ++dd) s += xL[sub][dd] * Wq[dd * 192 + c];
            qkv[row * 192 + c] = s;
        }
    }
}

// ---------- K2: T[row, e*32+p] = sum_d a[row,d]*G[d*1024+e*32+p] ----------
__global__ __launch_bounds__(256) void k2_T(
    const float* __restrict__ a, const float* __restrict__ G, float* __restrict__ T)
{
    int row = blockIdx.x;
    int tid = threadIdx.x;
    __shared__ float aL[32];
    if (tid < 32) aL[tid] = a[row * 32 + tid];
    __syncthreads();
    for (int k = 0; k < 4; ++k) {
        int idx = k * 256 + tid;
        float s = 0.f;
        #pragma unroll
        for (int d = 0; d < 32; ++d) s += aL[d] * G[d * 1024 + idx];
        T[row * 1024 + idx] = s;
    }
}

// ---------- K3: pair1 = pair_repr + op ----------
__global__ __launch_bounds__(256) void k3_op(
    const float* __restrict__ a, const float* __restrict__ am,
    const float* __restrict__ s2, const float* __restrict__ T,
    const float* __restrict__ GW, const float* __restrict__ BW,
    const float* __restrict__ pair_in, float* __restrict__ pair1)
{
    int blk = blockIdx.x;           // row*8 + jg
    int row = blk >> 3;             // b*256 + i
    int jg = blk & 7;
    int b = row >> 8;
    int j0 = jg * 32;
    int tid = threadIdx.x;
    __shared__ float Tl[1024];
    __shared__ float aL[32 * 33];
    __shared__ float amL[32], s2L[32], gwL[32], bwL[32];
    ((float4*)Tl)[tid] = ((const float4*)(T + (long)row * 1024))[tid];
    for (int k = 0; k < 4; ++k) {
        int idx = k * 256 + tid;
        aL[(idx >> 5) * 33 + (idx & 31)] = a[(b * 256 + j0) * 32 + idx];
    }
    if (tid < 32) {
        amL[tid] = am[b * 256 + j0 + tid];
        s2L[tid] = s2[b * 256 + j0 + tid];
        gwL[tid] = GW[tid];
        bwL[tid] = BW[tid];
    }
    __syncthreads();
    int jl = tid >> 3, cq = tid & 7;
    float am_i = am[row], s2_i = s2[row];
    float m = am_i * amL[jl];
    float isd = rsqrtf(s2_i * s2L[jl] - m * m + 1e-5f);
    long base = ((long)row * 256 + j0 + jl) * 32 + cq * 4;
    float4 pv = *(const float4*)(pair_in + base);
    float o[4];
    #pragma unroll
    for (int u = 0; u < 4; ++u) {
        int p = cq * 4 + u;
        float S = 0.f;
        #pragma unroll
        for (int e = 0; e < 32; ++e) S += aL[jl * 33 + e] * Tl[e * 32 + p];
        o[u] = isd * (S - m * gwL[p]) + bwL[p];
    }
    pv.x += o[0]; pv.y += o[1]; pv.z += o[2]; pv.w += o[3];
    *(float4*)(pair1 + base) = pv;
}

// ---------- K4: LN(pair1) inline; e1 = pn @ W_exp^T; fused stats1 ----------
__global__ __launch_bounds__(256) void k4_expand(
    const float* __restrict__ pair1, const float* __restrict__ g_pair,
    const float* __restrict__ b_pair, const float* __restrict__ W_exp,
    float* __restrict__ e1, float* __restrict__ st1s, float* __restrict__ st1q)
{
    int blk = blockIdx.x;            // b*1024 + pg
    int b = blk >> 10;
    int pixbase = (blk & 1023) * 64;
    int tid = threadIdx.x;
    __shared__ float xL[64 * 33];
    __shared__ float We[2048];
    __shared__ float muL[64], isdL[64];
    __shared__ float gL[32], bL[32];
    for (int k = 0; k < 8; ++k) We[k * 256 + tid] = W_exp[k * 256 + tid];
    if (tid < 32) { gL[tid] = g_pair[tid]; bL[tid] = b_pair[tid]; }
    const float4* src = (const float4*)(pair1 + ((long)b * LLSZ + pixbase) * 32);
    #pragma unroll
    for (int k = 0; k < 2; ++k) {
        int idx = k * 256 + tid;     // float4 idx; pix = idx>>3, cq = idx&7
        float4 v = src[idx];
        int pix = idx >> 3, cq = idx & 7;
        xL[pix * 33 + cq * 4 + 0] = v.x;
        xL[pix * 33 + cq * 4 + 1] = v.y;
        xL[pix * 33 + cq * 4 + 2] = v.z;
        xL[pix * 33 + cq * 4 + 3] = v.w;
    }
    __syncthreads();
    if (tid < 64) {
        float s = 0.f, q = 0.f;
        #pragma unroll
        for (int c = 0; c < 32; ++c) { float v = xL[tid * 33 + c]; s += v; q += v * v; }
        float mu = s * (1.f / 32.f);
        muL[tid] = mu;
        isdL[tid] = rsqrtf(q * (1.f / 32.f) - mu * mu + 1e-5f);
    }
    __syncthreads();
    #pragma unroll
    for (int k = 0; k < 8; ++k) {
        int idx = k * 256 + tid;
        int pix = idx >> 5, c = idx & 31;
        xL[pix * 33 + c] = (xL[pix * 33 + c] - muL[pix]) * isdL[pix] * gL[c] + bL[c];
    }
    __syncthreads();
    int pix = tid & 63, og = tid >> 6;   // wave og owns channels og*16..og*16+15
    float ssk = 0.f, qqk = 0.f;
    for (int oo = 0; oo < 16; ++oo) {
        int o = og * 16 + oo;
        float acc = 0.f;
        #pragma unroll
        for (int c = 0; c < 32; ++c) acc += xL[pix * 33 + c] * We[o * 32 + c];
        e1[((long)(b * 64 + o)) * LLSZ + pixbase + pix] = acc;
        float s = acc, q = acc * acc;
        for (int k = 32; k > 0; k >>= 1) { s += __shfl_xor(s, k, 64); q += __shfl_xor(q, k, 64); }
        if (pix == oo) { ssk = s; qqk = q; }
    }
    if (pix < 16) {
        atomicAdd(&st1s[b * 64 + og * 16 + pix], ssk);
        atomicAdd(&st1q[b * 64 + og * 16 + pix], qqk);
    }
}

// ---------- K6: depthwise 3x3 on silu(inorm(e1)) -> h2; fused stats2 ----------
__global__ __launch_bounds__(256) void k6_dw(
    const float* __restrict__ e1, const float* __restrict__ st1s,
    const float* __restrict__ st1q, const float* __restrict__ W_dw,
    float* __restrict__ h2, float* __restrict__ st2s, float* __restrict__ st2q)
{
    int blk = blockIdx.x;            // chan*32 + rg
    int chan = blk >> 5;             // 0..127
    int r0 = (blk & 31) * 8;
    int o = chan & 63;
    int tid = threadIdx.x;
    float m, isd;
    chan_stats(st1s, st1q, chan, m, isd);
    __shared__ float sL[10][258];
    const float* src = e1 + (long)chan * LLSZ;
    for (int k = tid; k < 640; k += 256) {   // 10 rows x 64 float4
        int rr = k >> 6, c4 = k & 63;
        int g = r0 - 1 + rr;
        float4 v = make_float4(0.f, 0.f, 0.f, 0.f);
        bool ok = (g >= 0 && g < 256);
        if (ok) v = *(const float4*)(src + g * 256 + c4 * 4);
        float t;
        t = (v.x - m) * isd; v.x = ok ? silu(t) : 0.f;
        t = (v.y - m) * isd; v.y = ok ? silu(t) : 0.f;
        t = (v.z - m) * isd; v.z = ok ? silu(t) : 0.f;
        t = (v.w - m) * isd; v.w = ok ? silu(t) : 0.f;
        sL[rr][1 + c4 * 4 + 0] = v.x;
        sL[rr][1 + c4 * 4 + 1] = v.y;
        sL[rr][1 + c4 * 4 + 2] = v.z;
        sL[rr][1 + c4 * 4 + 3] = v.w;
    }
    if (tid < 10) { sL[tid][0] = 0.f; sL[tid][257] = 0.f; }
    float w[9];
    #pragma unroll
    for (int k = 0; k < 9; ++k) w[k] = W_dw[o * 9 + k];
    __syncthreads();
    int c = tid;
    float bs = 0.f, bq = 0.f;
    #pragma unroll
    for (int rr = 0; rr < 8; ++rr) {
        float s = 0.f;
        #pragma unroll
        for (int ki = 0; ki < 3; ++ki)
            #pragma unroll
            for (int kj = 0; kj < 3; ++kj)
                s += sL[rr + ki][c + kj] * w[ki * 3 + kj];
        h2[(long)chan * LLSZ + (r0 + rr) * 256 + c] = s;
        bs += s; bq += s * s;
    }
    for (int k = 32; k > 0; k >>= 1) { bs += __shfl_xor(bs, k, 64); bq += __shfl_xor(bq, k, 64); }
    __shared__ float r2s[4], r2q[4];
    int wave = tid >> 6;
    if ((tid & 63) == 0) { r2s[wave] = bs; r2q[wave] = bq; }
    __syncthreads();
    if (tid == 0) {
        atomicAdd(&st2s[chan], r2s[0] + r2s[1] + r2s[2] + r2s[3]);
        atomicAdd(&st2q[chan], r2q[0] + r2q[1] + r2q[2] + r2q[3]);
    }
}

// ---------- K8: squeeze-sum of silu(inorm(h2)) ----------
__global__ __launch_bounds__(256) void k8_squeeze(
    const float* __restrict__ h2, const float* __restrict__ st2s,
    const float* __restrict__ st2q, float* __restrict__ sqs)
{
    int bid = blockIdx.x;
    int chan = bid >> 3, seg = bid & 7;
    int tid = threadIdx.x;
    float m, isd;
    chan_stats(st2s, st2q, chan, m, isd);
    const float4* p = (const float4*)(h2 + (long)chan * LLSZ + seg * 8192);
    float s = 0.f;
    #pragma unroll
    for (int k = 0; k < 8; ++k) {
        float4 v = p[k * 256 + tid];
        s += silu((v.x - m) * isd) + silu((v.y - m) * isd)
           + silu((v.z - m) * isd) + silu((v.w - m) * isd);
    }
    for (int k = 32; k > 0; k >>= 1) s += __shfl_xor(s, k, 64);
    __shared__ float rs[4];
    int wave = tid >> 6;
    if ((tid & 63) == 0) rs[wave] = s;
    __syncthreads();
    if (tid == 0) atomicAdd(&sqs[chan], rs[0] + rs[1] + rs[2] + rs[3]);
}

// ---------- K10: SE-MLP inline + pointwise conv + fused stats3. 64 pix/block ----------
__global__ __launch_bounds__(256) void k10_pw(
    const float* __restrict__ h2, const float* __restrict__ st2s,
    const float* __restrict__ st2q, const float* __restrict__ sqs,
    const float* __restrict__ W_se1, const float* __restrict__ b_se1,
    const float* __restrict__ W_se2, const float* __restrict__ b_se2,
    const float* __restrict__ W_pw, float* __restrict__ hp,
    float* __restrict__ st3s, float* __restrict__ st3q)
{
    int blk = blockIdx.x;            // b*1024 + pg
    int b = blk >> 10;
    int pixbase = (blk & 1023) * 64;
    int tid = threadIdx.x;
    __shared__ float hL[64 * 65];
    __shared__ float Wp[2048];
    __shared__ float s1L[16];
    __shared__ float sqvL[64];
    for (int k = 0; k < 8; ++k) Wp[k * 256 + tid] = W_pw[k * 256 + tid];
    if (tid < 16) {
        float s = 0.f;
        for (int c = 0; c < 64; ++c) s += sqs[b * 64 + c] * W_se1[tid * 64 + c];
        s = s * INV_LL + b_se1[tid];
        s1L[tid] = silu(s);
    }
    __syncthreads();
    if (tid < 64) {
        float s = 0.f;
        #pragma unroll
        for (int j = 0; j < 16; ++j) s += s1L[j] * W_se2[tid * 16 + j];
        s += b_se2[tid];
        sqvL[tid] = 1.f / (1.f + expf(-s));
    }
    __syncthreads();
    #pragma unroll
    for (int k = 0; k < 4; ++k) {
        int idx = k * 256 + tid;     // 1024 float4s: c = idx>>4, f4 = idx&15
        int c = idx >> 4, f4 = idx & 15;
        int chan = b * 64 + c;
        float m, isd;
        chan_stats(st2s, st2q, chan, m, isd);
        float sc = sqvL[c];
        float4 v = *(const float4*)(h2 + (long)chan * LLSZ + pixbase + f4 * 4);
        hL[c * 65 + f4 * 4 + 0] = silu((v.x - m) * isd) * sc;
        hL[c * 65 + f4 * 4 + 1] = silu((v.y - m) * isd) * sc;
        hL[c * 65 + f4 * 4 + 2] = silu((v.z - m) * isd) * sc;
        hL[c * 65 + f4 * 4 + 3] = silu((v.w - m) * isd) * sc;
    }
    __syncthreads();
    int pix = tid & 63, og = tid >> 6;   // wave og owns p = og*8..og*8+7
    float acc[8];
    #pragma unroll
    for (int u = 0; u < 8; ++u) acc[u] = 0.f;
    #pragma unroll
    for (int c = 0; c < 64; ++c) {
        float hv = hL[c * 65 + pix];
        #pragma unroll
        for (int u = 0; u < 8; ++u) acc[u] += hv * Wp[(og * 8 + u) * 64 + c];
    }
    float ssk = 0.f, qqk = 0.f;
    #pragma unroll
    for (int u = 0; u < 8; ++u) {
        float v = acc[u];
        int p = og * 8 + u;
        hp[((long)(b * 32 + p)) * LLSZ + pixbase + pix] = v;
        float s = v, q = v * v;
        for (int k = 32; k > 0; k >>= 1) { s += __shfl_xor(s, k, 64); q += __shfl_xor(q, k, 64); }
        if (pix == u) { ssk = s; qqk = q; }
    }
    if (pix < 8) {
        atomicAdd(&st3s[b * 32 + og * 8 + pix], ssk);
        atomicAdd(&st3q[b * 32 + og * 8 + pix], qqk);
    }
}

// ---------- K12: pair_out = pair1 + LN(pair1) + inorm(hp); bias = LN(pair_out)@W_bias ----------
__global__ __launch_bounds__(256) void k12_merge(
    const float* __restrict__ pair1, const float* __restrict__ hp,
    const float* __restrict__ st3s, const float* __restrict__ st3q,
    const float* __restrict__ g_pair, const float* __restrict__ b_pair,
    const float* __restrict__ W_bias, float* __restrict__ pair_out,
    float* __restrict__ biasbuf)
{
    int blk = blockIdx.x;            // b*2048 + pg
    int b = blk >> 11;
    int pixbase = (blk & 2047) * 32;
    int tid = threadIdx.x;
    __shared__ float hpL[32 * 33];
    {
        int c = tid >> 3, f4 = tid & 7;   // 32 chan x 8 float4
        int chan = b * 32 + c;
        float m, isd;
        chan_stats(st3s, st3q, chan, m, isd);
        float4 v = *(const float4*)(hp + (long)chan * LLSZ + pixbase + f4 * 4);
        hpL[c * 33 + f4 * 4 + 0] = (v.x - m) * isd;
        hpL[c * 33 + f4 * 4 + 1] = (v.y - m) * isd;
        hpL[c * 33 + f4 * 4 + 2] = (v.z - m) * isd;
        hpL[c * 33 + f4 * 4 + 3] = (v.w - m) * isd;
    }
    __syncthreads();
    int pg = tid >> 3, cq = tid & 7;     // pixel pg 0..31, channel quad cq
    float gp[4], bp[4], wb[4][4];
    #pragma unroll
    for (int u = 0; u < 4; ++u) {
        int c = cq * 4 + u;
        gp[u] = g_pair[c]; bp[u] = b_pair[c];
        #pragma unroll
        for (int h = 0; h < 4; ++h) wb[u][h] = W_bias[c * 4 + h];
    }
    int pix = pg;
    long base = ((long)b * LLSZ + pixbase + pix) * 32;
    float4 v1 = *(const float4*)(pair1 + base + cq * 4);
    float s = v1.x + v1.y + v1.z + v1.w;
    float q = v1.x * v1.x + v1.y * v1.y + v1.z * v1.z + v1.w * v1.w;
    s += __shfl_xor(s, 1, 8); q += __shfl_xor(q, 1, 8);
    s += __shfl_xor(s, 2, 8); q += __shfl_xor(q, 2, 8);
    s += __shfl_xor(s, 4, 8); q += __shfl_xor(q, 4, 8);
    float mu = s * (1.f / 32.f);
    float isd = rsqrtf(q * (1.f / 32.f) - mu * mu + 1e-5f);
    float vo[4], vv1[4] = {v1.x, v1.y, v1.z, v1.w};
    #pragma unroll
    for (int u = 0; u < 4; ++u) {
        float pnv = (vv1[u] - mu) * isd * gp[u] + bp[u];
        vo[u] = vv1[u] + pnv + hpL[(cq * 4 + u) * 33 + pix];
    }
    *(float4*)(pair_out + base + cq * 4) = make_float4(vo[0], vo[1], vo[2], vo[3]);
    float s2_ = vo[0] + vo[1] + vo[2] + vo[3];
    float q2 = vo[0] * vo[0] + vo[1] * vo[1] + vo[2] * vo[2] + vo[3] * vo[3];
    s2_ += __shfl_xor(s2_, 1, 8); q2 += __shfl_xor(q2, 1, 8);
    s2_ += __shfl_xor(s2_, 2, 8); q2 += __shfl_xor(q2, 2, 8);
    s2_ += __shfl_xor(s2_, 4, 8); q2 += __shfl_xor(q2, 4, 8);
    float mu2 = s2_ * (1.f / 32.f);
    float isd2 = rsqrtf(q2 * (1.f / 32.f) - mu2 * mu2 + 1e-5f);
    float t[4] = {0.f, 0.f, 0.f, 0.f};
    #pragma unroll
    for (int u = 0; u < 4; ++u) {
        float pn2 = (vo[u] - mu2) * isd2 * gp[u] + bp[u];
        #pragma unroll
        for (int h = 0; h < 4; ++h) t[h] += pn2 * wb[u][h];
    }
    #pragma unroll
    for (int h = 0; h < 4; ++h) {
        t[h] += __shfl_xor(t[h], 1, 8);
        t[h] += __shfl_xor(t[h], 2, 8);
        t[h] += __shfl_xor(t[h], 4, 8);
    }
    if (cq == 0) {
        #pragma unroll
        for (int h = 0; h < 4; ++h)
            biasbuf[((long)(b * 4 + h)) * LLSZ + pixbase + pix] = t[h];
    }
}

// ---------- K13: attention, one wave per (b,h,i) ----------
__global__ __launch_bounds__(256) void k13_attn(
    const float* __restrict__ qkv, const float* __restrict__ biasbuf,
    float* __restrict__ ctx)
{
    int blk = blockIdx.x;           // b*256 + h*64 + ig
    int b = blk >> 8;
    int h = (blk >> 6) & 3;
    int ig = blk & 63;
    int wave = threadIdx.x >> 6, lane = threadIdx.x & 63;
    int i = ig * 4 + wave;
    const float* qrow = qkv + ((long)(b * 256 + i)) * 192 + h * 16;
    float qv[16];
    #pragma unroll
    for (int d = 0; d < 16; ++d) qv[d] = qrow[d];
    float sj[4];
    #pragma unroll
    for (int q = 0; q < 4; ++q) {
        int j = lane + 64 * q;
        const float* kr = qkv + ((long)(b * 256 + j)) * 192 + 64 + h * 16;
        float s = 0.f;
        #pragma unroll
        for (int d = 0; d < 16; ++d) s += qv[d] * kr[d];
        sj[q] = s * 0.25f + biasbuf[((long)(b * 4 + h)) * LLSZ + i * 256 + j];
    }
    float mx = fmaxf(fmaxf(sj[0], sj[1]), fmaxf(sj[2], sj[3]));
    for (int k = 32; k > 0; k >>= 1) mx = fmaxf(mx, __shfl_xor(mx, k, 64));
    float wgt[4], wsum = 0.f;
    #pragma unroll
    for (int q = 0; q < 4; ++q) { wgt[q] = expf(sj[q] - mx); wsum += wgt[q]; }
    for (int k = 32; k > 0; k >>= 1) wsum += __shfl_xor(wsum, k, 64);
    float inv = 1.f / wsum;
    float o[16];
    #pragma unroll
    for (int d = 0; d < 16; ++d) o[d] = 0.f;
    #pragma unroll
    for (int q = 0; q < 4; ++q) {
        const float* vr = qkv + ((long)(b * 256 + lane + 64 * q)) * 192 + 128 + h * 16;
        #pragma unroll
        for (int d = 0; d < 16; ++d) o[d] += wgt[q] * vr[d];
    }
    #pragma unroll
    for (int d = 0; d < 16; ++d)
        for (int k = 32; k > 0; k >>= 1) o[d] += __shfl_xor(o[d], k, 64);
    if (lane == 0) {
        #pragma unroll
        for (int d = 0; d < 16; ++d)
            ctx[((long)(b * 256 + i)) * 64 + h * 16 + d] = o[d] * inv;
    }
}

// ---------- K14: seq_out = seq + ctx@W_outp + b_outp ----------
__global__ __launch_bounds__(256) void k14_seqout(
    const float* __restrict__ seq, const float* __restrict__ ctx,
    const float* __restrict__ W_outp, const float* __restrict__ b_outp,
    float* __restrict__ out)
{
    __shared__ float Wo[64 * 64];
    __shared__ float cL[4][64];
    int tid = threadIdx.x;
    #pragma unroll
    for (int k = 0; k < 16; ++k) Wo[k * 256 + tid] = W_outp[k * 256 + tid];
    int sub = tid >> 6, t = tid & 63;
    int row = blockIdx.x * 4 + sub;
    cL[sub][t] = ctx[row * 64 + t];
    __syncthreads();
    float s = b_outp[t];
    #pragma unroll
    for (int u = 0; u < 64; ++u) s += cL[sub][u] * Wo[u * 64 + t];
    out[row * 64 + t] = seq[row * 64 + t] + s;
}

extern "C" void kernel_launch(void* const* d_in, const int* in_sizes, int n_in,
                              void* d_out, int out_size, void* d_ws, size_t ws_size,
                              hipStream_t stream) {
    const float* seq_repr   = (const float*)d_in[0];
    const float* pair_repr  = (const float*)d_in[1];
    const float* g_attn     = (const float*)d_in[2];
    const float* b_attn     = (const float*)d_in[3];
    const float* g_pair     = (const float*)d_in[4];
    const float* b_pair     = (const float*)d_in[5];
    const float* W_opm_lin  = (const float*)d_in[6];
    const float* b_opm_lin  = (const float*)d_in[7];
    const float* g_opm      = (const float*)d_in[8];
    const float* b_opm      = (const float*)d_in[9];
    const float* W_opm_proj = (const float*)d_in[10];
    const float* b_opm_proj = (const float*)d_in[11];
    const float* W_exp      = (const float*)d_in[12];
    const float* W_dw       = (const float*)d_in[13];
    const float* W_se1      = (const float*)d_in[14];
    const float* b_se1      = (const float*)d_in[15];
    const float* W_se2      = (const float*)d_in[16];
    const float* b_se2      = (const float*)d_in[17];
    const float* W_pw       = (const float*)d_in[18];
    const float* W_qkv      = (const float*)d_in[19];
    const float* W_outp     = (const float*)d_in[20];
    const float* b_outp     = (const float*)d_in[21];
    const float* W_bias     = (const float*)d_in[22];

    float* out_seq  = (float*)d_out;
    float* out_pair = (float*)d_out + 32768;

    // Workspace (floats). hp aliases e1 (dead after k6); biasb aliases T (dead after k3).
    float* w = (float*)d_ws;
    float* a_buf   = w;                    // 16384
    float* am_buf  = a_buf + 16384;        // 512
    float* s2_buf  = am_buf + 512;         // 512
    float* qkv_buf = s2_buf + 512;         // 98304
    float* G_buf   = qkv_buf + 98304;      // 32768
    float* GW_buf  = G_buf + 32768;        // 32
    float* BW_buf  = GW_buf + 32;          // 32
    float* ctx     = BW_buf + 32;          // 32768
    float* st1s    = ctx + 32768;          // 128  } stats region (zeroed by kA blk0)
    float* st1q    = st1s + 128;           // 128
    float* st2s    = st1q + 128;           // 128
    float* st2q    = st2s + 128;           // 128
    float* st3s    = st2q + 128;           // 64
    float* st3q    = st3s + 64;            // 64
    float* sqs     = st3q + 64;            // 128  } total 768
    float* T_buf   = sqs + 128;            // 524288
    float* biasb   = T_buf;                // alias
    float* pair1   = T_buf + 524288;       // 4194304
    float* e1      = pair1 + 4194304;      // 8388608
    float* hp      = e1;                   // alias (4194304)
    float* h2      = e1 + 8388608;         // 8388608

    hipLaunchKernelGGL(kA, dim3(129), dim3(256), 0, stream,
                       g_opm, b_opm, W_opm_proj, b_opm_proj, G_buf, GW_buf, BW_buf,
                       st1s,
                       seq_repr, g_attn, b_attn, W_opm_lin, b_opm_lin, W_qkv,
                       a_buf, am_buf, s2_buf, qkv_buf);
    hipLaunchKernelGGL(k2_T, dim3(512), dim3(256), 0, stream, a_buf, G_buf, T_buf);
    hipLaunchKernelGGL(k3_op, dim3(4096), dim3(256), 0, stream,
                       a_buf, am_buf, s2_buf, T_buf, GW_buf, BW_buf,
                       pair_repr, pair1);
    hipLaunchKernelGGL(k4_expand, dim3(2048), dim3(256), 0, stream,
                       pair1, g_pair, b_pair, W_exp, e1, st1s, st1q);
    hipLaunchKernelGGL(k6_dw, dim3(4096), dim3(256), 0, stream,
                       e1, st1s, st1q, W_dw, h2, st2s, st2q);
    hipLaunchKernelGGL(k8_squeeze, dim3(1024), dim3(256), 0, stream,
                       h2, st2s, st2q, sqs);
    hipLaunchKernelGGL(k10_pw, dim3(2048), dim3(256), 0, stream,
                       h2, st2s, st2q, sqs, W_se1, b_se1, W_se2, b_se2,
                       W_pw, hp, st3s, st3q);
    hipLaunchKernelGGL(k12_merge, dim3(4096), dim3(256), 0, stream,
                       pair1, hp, st3s, st3q, g_pair, b_pair, W_bias,
                       out_pair, biasb);
    hipLaunchKernelGGL(k13_attn, dim3(512), dim3(256), 0, stream,
                       qkv_buf, biasb, ctx);
    hipLaunchKernelGGL(k14_seqout, dim3(128), dim3(256), 0, stream,
                       seq_repr, ctx, W_outp, b_outp, out_seq);
}

// Round 6
// 299.825 us; speedup vs baseline: 1.1247x; 1.1247x over previous
//
#include <hip/hip_runtime.h>
#include <hip/hip_bf16.h>

#define LLSZ 65536  // L*L
#define INV_LL (1.f / 65536.f)

// B=2, L=256, SD=64, PD=32, H=4, HD=16, OH=32, EXP=64, SE=16

__device__ __forceinline__ void chan_stats(const float* sum, const float* sumsq,
                                           int chan, float& m, float& isd)
{
    m = sum[chan] * INV_LL;
    float var = sumsq[chan] * INV_LL - m * m;
    isd = rsqrtf(var + 1e-5f);
}

__device__ __forceinline__ float silu(float t) { return t / (1.f + expf(-t)); }

// ---------- kA: block 0 = {zero stats, G/GW/BW prep}; blocks 1..128 = seq LN -> a, qkv ----------
__global__ __launch_bounds__(256) void kA(
    const float* __restrict__ g_opm, const float* __restrict__ b_opm,
    const float* __restrict__ Wproj, const float* __restrict__ b_proj,
    float* __restrict__ G, float* __restrict__ GW, float* __restrict__ BW,
    float* __restrict__ stats0,   // 768 floats to zero
    const float* __restrict__ seq, const float* __restrict__ g_attn,
    const float* __restrict__ b_attn, const float* __restrict__ W_lin,
    const float* __restrict__ b_lin, const float* __restrict__ W_qkv,
    float* __restrict__ a, float* __restrict__ am, float* __restrict__ s2,
    float* __restrict__ qkv)
{
    int tid = threadIdx.x;
    if (blockIdx.x == 0) {
        for (int k = tid; k < 768; k += 256) stats0[k] = 0.f;
        int p = tid & 31, rg = tid >> 5;  // rg 0..7
        float gw = 0.f, bw = 0.f;
        #pragma unroll 8
        for (int k = 0; k < 128; ++k) {
            int de = k * 8 + rg;
            float wv = Wproj[de * 32 + p];
            float gv = g_opm[de] * wv;
            G[de * 32 + p] = gv;
            gw += gv;
            bw += b_opm[de] * wv;
        }
        __shared__ float rG[256], rB[256];
        rG[rg * 32 + p] = gw;
        rB[rg * 32 + p] = bw;
        __syncthreads();
        for (int s = 4; s > 0; s >>= 1) {
            if (rg < s) {
                rG[rg * 32 + p] += rG[(rg + s) * 32 + p];
                rB[rg * 32 + p] += rB[(rg + s) * 32 + p];
            }
            __syncthreads();
        }
        if (tid < 32) { GW[p] = rG[p]; BW[p] = rB[p] + b_proj[p]; }
    } else {
        __shared__ float Wq[64 * 192];
        __shared__ float Wl[64 * 32];
        __shared__ float xL[4][64];
        #pragma unroll
        for (int k = 0; k < 48; ++k) Wq[k * 256 + tid] = W_qkv[k * 256 + tid];
        #pragma unroll
        for (int k = 0; k < 8; ++k) Wl[k * 256 + tid] = W_lin[k * 256 + tid];
        int sub = tid >> 6, t = tid & 63;
        int row = (blockIdx.x - 1) * 4 + sub;
        float v = seq[row * 64 + t];
        float m = v;
        for (int k = 32; k > 0; k >>= 1) m += __shfl_xor(m, k, 64);
        m *= (1.f / 64.f);
        float d = v - m;
        float var = d * d;
        for (int k = 32; k > 0; k >>= 1) var += __shfl_xor(var, k, 64);
        var *= (1.f / 64.f);
        float x = d * rsqrtf(var + 1e-5f) * g_attn[t] + b_attn[t];
        xL[sub][t] = x;
        __syncthreads();
        if (t < 32) {
            float s = 0.f;
            #pragma unroll
            for (int dd = 0; dd < 64; ++dd) s += xL[sub][dd] * Wl[dd * 32 + t];
            s += b_lin[t];
            a[row * 32 + t] = s;
            float mm = s, ss = s * s;
            for (int k = 16; k > 0; k >>= 1) {
                mm += __shfl_xor(mm, k, 32);
                ss += __shfl_xor(ss, k, 32);
            }
            if (t == 0) { am[row] = mm * (1.f / 32.f); s2[row] = ss * (1.f / 32.f); }
        }
        #pragma unroll
        for (int c3 = 0; c3 < 3; ++c3) {
            int c = c3 * 64 + t;
            float s = 0.f;
            #pragma unroll
            for (int dd = 0; dd < 64; ++dd) s += xL[sub][dd] * Wq[dd * 192 + c];
            qkv[row * 192 + c] = s;
        }
    }
}

// ---------- K2: T[row, e*32+p] = sum_d a[row,d]*G[d*1024+e*32+p] ----------
__global__ __launch_bounds__(256) void k2_T(
    const float* __restrict__ a, const float* __restrict__ G, float* __restrict__ T)
{
    int row = blockIdx.x;
    int tid = threadIdx.x;
    __shared__ float aL[32];
    if (tid < 32) aL[tid] = a[row * 32 + tid];
    __syncthreads();
    for (int k = 0; k < 4; ++k) {
        int idx = k * 256 + tid;
        float s = 0.f;
        #pragma unroll
        for (int d = 0; d < 32; ++d) s += aL[d] * G[d * 1024 + idx];
        T[row * 1024 + idx] = s;
    }
}

// ---------- K3: pair1 = pair_repr + op ----------
__global__ __launch_bounds__(256) void k3_op(
    const float* __restrict__ a, const float* __restrict__ am,
    const float* __restrict__ s2, const float* __restrict__ T,
    const float* __restrict__ GW, const float* __restrict__ BW,
    const float* __restrict__ pair_in, float* __restrict__ pair1)
{
    int blk = blockIdx.x;           // row*8 + jg
    int row = blk >> 3;             // b*256 + i
    int jg = blk & 7;
    int b = row >> 8;
    int j0 = jg * 32;
    int tid = threadIdx.x;
    __shared__ float Tl[1024];
    __shared__ float aL[32 * 33];
    __shared__ float amL[32], s2L[32], gwL[32], bwL[32];
    ((float4*)Tl)[tid] = ((const float4*)(T + (long)row * 1024))[tid];
    for (int k = 0; k < 4; ++k) {
        int idx = k * 256 + tid;
        aL[(idx >> 5) * 33 + (idx & 31)] = a[(b * 256 + j0) * 32 + idx];
    }
    if (tid < 32) {
        amL[tid] = am[b * 256 + j0 + tid];
        s2L[tid] = s2[b * 256 + j0 + tid];
        gwL[tid] = GW[tid];
        bwL[tid] = BW[tid];
    }
    __syncthreads();
    int jl = tid >> 3, cq = tid & 7;
    float am_i = am[row], s2_i = s2[row];
    float m = am_i * amL[jl];
    float isd = rsqrtf(s2_i * s2L[jl] - m * m + 1e-5f);
    long base = ((long)row * 256 + j0 + jl) * 32 + cq * 4;
    float4 pv = *(const float4*)(pair_in + base);
    float o[4];
    #pragma unroll
    for (int u = 0; u < 4; ++u) {
        int p = cq * 4 + u;
        float S = 0.f;
        #pragma unroll
        for (int e = 0; e < 32; ++e) S += aL[jl * 33 + e] * Tl[e * 32 + p];
        o[u] = isd * (S - m * gwL[p]) + bwL[p];
    }
    pv.x += o[0]; pv.y += o[1]; pv.z += o[2]; pv.w += o[3];
    *(float4*)(pair1 + base) = pv;
}

// ---------- K4: thread-per-pixel. LN(pair1) in-thread; e1 = pn @ W_exp^T (s_load weights) ----------
// grid = 1024: b = blk>>9, oh = (blk>>8)&1 (owns 32 of 64 outputs), pg = blk&255
__global__ __launch_bounds__(256) void k4_expand(
    const float* __restrict__ pair1, const float* __restrict__ g_pair,
    const float* __restrict__ b_pair, const float* __restrict__ W_exp,
    float* __restrict__ e1)
{
    int b = blockIdx.x >> 9;
    int oh = (blockIdx.x >> 8) & 1;
    int px = (blockIdx.x & 255) * 256 + threadIdx.x;
    long pixel = (long)b * LLSZ + px;
    float x[32];
    const float4* src = (const float4*)(pair1 + pixel * 32);
    #pragma unroll
    for (int k = 0; k < 8; ++k) {
        float4 v = src[k];
        x[k * 4 + 0] = v.x; x[k * 4 + 1] = v.y;
        x[k * 4 + 2] = v.z; x[k * 4 + 3] = v.w;
    }
    float s = 0.f, q = 0.f;
    #pragma unroll
    for (int c = 0; c < 32; ++c) { s += x[c]; q += x[c] * x[c]; }
    float mu = s * (1.f / 32.f);
    float isd = rsqrtf(q * (1.f / 32.f) - mu * mu + 1e-5f);
    #pragma unroll
    for (int c = 0; c < 32; ++c)
        x[c] = (x[c] - mu) * isd * g_pair[c] + b_pair[c];   // g/b: uniform s_load
    float* dst = e1 + ((long)(b * 64 + oh * 32)) * LLSZ + px;
    #pragma unroll
    for (int oo = 0; oo < 32; ++oo) {
        int o = oh * 32 + oo;
        float acc = 0.f;
        #pragma unroll
        for (int c = 0; c < 32; ++c) acc += x[c] * W_exp[o * 32 + c];  // s_load
        dst[(long)oo * LLSZ] = acc;
    }
}

// ---------- stats: per-channel sum/sumsq, 8 segments + atomics (pre-zeroed) ----------
__global__ __launch_bounds__(256) void k_stats(
    const float* __restrict__ buf, float* __restrict__ sum, float* __restrict__ sumsq)
{
    int bid = blockIdx.x;
    int chan = bid >> 3, seg = bid & 7;
    int tid = threadIdx.x;
    const float4* p = (const float4*)(buf + (long)chan * LLSZ + seg * 8192);
    float s = 0.f, ss = 0.f;
    #pragma unroll
    for (int k = 0; k < 8; ++k) {
        float4 v = p[k * 256 + tid];
        s += v.x + v.y + v.z + v.w;
        ss += v.x * v.x + v.y * v.y + v.z * v.z + v.w * v.w;
    }
    for (int k = 32; k > 0; k >>= 1) { s += __shfl_xor(s, k, 64); ss += __shfl_xor(ss, k, 64); }
    __shared__ float rs[4], rq[4];
    int wave = tid >> 6;
    if ((tid & 63) == 0) { rs[wave] = s; rq[wave] = ss; }
    __syncthreads();
    if (tid == 0) {
        atomicAdd(&sum[chan], rs[0] + rs[1] + rs[2] + rs[3]);
        atomicAdd(&sumsq[chan], rq[0] + rq[1] + rq[2] + rq[3]);
    }
}

// ---------- K6: depthwise 3x3 on silu(inorm(e1)) -> h2; fused stats2 ----------
__global__ __launch_bounds__(256) void k6_dw(
    const float* __restrict__ e1, const float* __restrict__ st1s,
    const float* __restrict__ st1q, const float* __restrict__ W_dw,
    float* __restrict__ h2, float* __restrict__ st2s, float* __restrict__ st2q)
{
    int blk = blockIdx.x;            // chan*32 + rg
    int chan = blk >> 5;             // 0..127
    int r0 = (blk & 31) * 8;
    int o = chan & 63;
    int tid = threadIdx.x;
    float m, isd;
    chan_stats(st1s, st1q, chan, m, isd);
    __shared__ float sL[10][258];
    const float* src = e1 + (long)chan * LLSZ;
    for (int k = tid; k < 640; k += 256) {   // 10 rows x 64 float4
        int rr = k >> 6, c4 = k & 63;
        int g = r0 - 1 + rr;
        float4 v = make_float4(0.f, 0.f, 0.f, 0.f);
        bool ok = (g >= 0 && g < 256);
        if (ok) v = *(const float4*)(src + g * 256 + c4 * 4);
        float t;
        t = (v.x - m) * isd; v.x = ok ? silu(t) : 0.f;
        t = (v.y - m) * isd; v.y = ok ? silu(t) : 0.f;
        t = (v.z - m) * isd; v.z = ok ? silu(t) : 0.f;
        t = (v.w - m) * isd; v.w = ok ? silu(t) : 0.f;
        sL[rr][1 + c4 * 4 + 0] = v.x;
        sL[rr][1 + c4 * 4 + 1] = v.y;
        sL[rr][1 + c4 * 4 + 2] = v.z;
        sL[rr][1 + c4 * 4 + 3] = v.w;
    }
    if (tid < 10) { sL[tid][0] = 0.f; sL[tid][257] = 0.f; }
    float w[9];
    #pragma unroll
    for (int k = 0; k < 9; ++k) w[k] = W_dw[o * 9 + k];
    __syncthreads();
    int c = tid;
    float bs = 0.f, bq = 0.f;
    #pragma unroll
    for (int rr = 0; rr < 8; ++rr) {
        float s = 0.f;
        #pragma unroll
        for (int ki = 0; ki < 3; ++ki)
            #pragma unroll
            for (int kj = 0; kj < 3; ++kj)
                s += sL[rr + ki][c + kj] * w[ki * 3 + kj];
        h2[(long)chan * LLSZ + (r0 + rr) * 256 + c] = s;
        bs += s; bq += s * s;
    }
    for (int k = 32; k > 0; k >>= 1) { bs += __shfl_xor(bs, k, 64); bq += __shfl_xor(bq, k, 64); }
    __shared__ float r2s[4], r2q[4];
    int wave = tid >> 6;
    if ((tid & 63) == 0) { r2s[wave] = bs; r2q[wave] = bq; }
    __syncthreads();
    if (tid == 0) {
        atomicAdd(&st2s[chan], r2s[0] + r2s[1] + r2s[2] + r2s[3]);
        atomicAdd(&st2q[chan], r2q[0] + r2q[1] + r2q[2] + r2q[3]);
    }
}

// ---------- K8: squeeze-sum of silu(inorm(h2)) ----------
__global__ __launch_bounds__(256) void k8_squeeze(
    const float* __restrict__ h2, const float* __restrict__ st2s,
    const float* __restrict__ st2q, float* __restrict__ sqs)
{
    int bid = blockIdx.x;
    int chan = bid >> 3, seg = bid & 7;
    int tid = threadIdx.x;
    float m, isd;
    chan_stats(st2s, st2q, chan, m, isd);
    const float4* p = (const float4*)(h2 + (long)chan * LLSZ + seg * 8192);
    float s = 0.f;
    #pragma unroll
    for (int k = 0; k < 8; ++k) {
        float4 v = p[k * 256 + tid];
        s += silu((v.x - m) * isd) + silu((v.y - m) * isd)
           + silu((v.z - m) * isd) + silu((v.w - m) * isd);
    }
    for (int k = 32; k > 0; k >>= 1) s += __shfl_xor(s, k, 64);
    __shared__ float rs[4];
    int wave = tid >> 6;
    if ((tid & 63) == 0) rs[wave] = s;
    __syncthreads();
    if (tid == 0) atomicAdd(&sqs[chan], rs[0] + rs[1] + rs[2] + rs[3]);
}

// ---------- K10: thread-per-pixel pointwise conv, s_load weights, SE inline ----------
// grid = 512: b = blk>>8, pg = blk&255
__global__ __launch_bounds__(256) void k10_pw(
    const float* __restrict__ h2, const float* __restrict__ st2s,
    const float* __restrict__ st2q, const float* __restrict__ sqs,
    const float* __restrict__ W_se1, const float* __restrict__ b_se1,
    const float* __restrict__ W_se2, const float* __restrict__ b_se2,
    const float* __restrict__ W_pw, float* __restrict__ hp)
{
    int b = blockIdx.x >> 8;
    int px = (blockIdx.x & 255) * 256 + threadIdx.x;
    int tid = threadIdx.x;
    __shared__ float s1L[16];
    __shared__ float sqvL[64];
    if (tid < 16) {
        float s = 0.f;
        for (int c = 0; c < 64; ++c) s += sqs[b * 64 + c] * W_se1[tid * 64 + c];
        s = s * INV_LL + b_se1[tid];
        s1L[tid] = silu(s);
    }
    __syncthreads();
    if (tid < 64) {
        float s = 0.f;
        #pragma unroll
        for (int j = 0; j < 16; ++j) s += s1L[j] * W_se2[tid * 16 + j];
        s += b_se2[tid];
        sqvL[tid] = 1.f / (1.f + expf(-s));
    }
    __syncthreads();
    float x[64];
    const float* src = h2 + ((long)b * 64) * LLSZ + px;
    #pragma unroll
    for (int c = 0; c < 64; ++c) {
        float m, isd;
        chan_stats(st2s, st2q, b * 64 + c, m, isd);   // uniform s_load
        float v = src[(long)c * LLSZ];
        x[c] = silu((v - m) * isd) * sqvL[c];
    }
    float* dst = hp + ((long)b * 32) * LLSZ + px;
    #pragma unroll
    for (int p = 0; p < 32; ++p) {
        float acc = 0.f;
        #pragma unroll
        for (int c = 0; c < 64; ++c) acc += x[c] * W_pw[p * 64 + c];  // s_load
        dst[(long)p * LLSZ] = acc;
    }
}

// ---------- K12: thread-per-pixel merge. No LDS, no shuffles ----------
// grid = 512: b = blk>>8
__global__ __launch_bounds__(256) void k12_merge(
    const float* __restrict__ pair1, const float* __restrict__ hp,
    const float* __restrict__ st3s, const float* __restrict__ st3q,
    const float* __restrict__ g_pair, const float* __restrict__ b_pair,
    const float* __restrict__ W_bias, float* __restrict__ pair_out,
    float* __restrict__ biasbuf)
{
    int b = blockIdx.x >> 8;
    int px = (blockIdx.x & 255) * 256 + threadIdx.x;
    long pixel = (long)b * LLSZ + px;
    float v1[32];
    const float4* src = (const float4*)(pair1 + pixel * 32);
    #pragma unroll
    for (int k = 0; k < 8; ++k) {
        float4 v = src[k];
        v1[k * 4 + 0] = v.x; v1[k * 4 + 1] = v.y;
        v1[k * 4 + 2] = v.z; v1[k * 4 + 3] = v.w;
    }
    float s = 0.f, q = 0.f;
    #pragma unroll
    for (int c = 0; c < 32; ++c) { s += v1[c]; q += v1[c] * v1[c]; }
    float mu = s * (1.f / 32.f);
    float isd = rsqrtf(q * (1.f / 32.f) - mu * mu + 1e-5f);
    float vo[32];
    const float* hpb = hp + ((long)b * 32) * LLSZ + px;
    #pragma unroll
    for (int p = 0; p < 32; ++p) {
        float m3, isd3;
        chan_stats(st3s, st3q, b * 32 + p, m3, isd3);  // uniform s_load
        float hv = hpb[(long)p * LLSZ];
        float pnv = (v1[p] - mu) * isd * g_pair[p] + b_pair[p];
        vo[p] = v1[p] + pnv + (hv - m3) * isd3;
    }
    float4* dst = (float4*)(pair_out + pixel * 32);
    #pragma unroll
    for (int k = 0; k < 8; ++k)
        dst[k] = make_float4(vo[k * 4], vo[k * 4 + 1], vo[k * 4 + 2], vo[k * 4 + 3]);
    float s2_ = 0.f, q2 = 0.f;
    #pragma unroll
    for (int c = 0; c < 32; ++c) { s2_ += vo[c]; q2 += vo[c] * vo[c]; }
    float mu2 = s2_ * (1.f / 32.f);
    float isd2 = rsqrtf(q2 * (1.f / 32.f) - mu2 * mu2 + 1e-5f);
    float t[4] = {0.f, 0.f, 0.f, 0.f};
    #pragma unroll
    for (int p = 0; p < 32; ++p) {
        float pn2 = (vo[p] - mu2) * isd2 * g_pair[p] + b_pair[p];
        #pragma unroll
        for (int h = 0; h < 4; ++h) t[h] += pn2 * W_bias[p * 4 + h];  // s_load
    }
    #pragma unroll
    for (int h = 0; h < 4; ++h)
        biasbuf[((long)(b * 4 + h)) * LLSZ + px] = t[h];
}

// ---------- K13: attention, one wave per (b,h,i) ----------
__global__ __launch_bounds__(256) void k13_attn(
    const float* __restrict__ qkv, const float* __restrict__ biasbuf,
    float* __restrict__ ctx)
{
    int blk = blockIdx.x;           // b*256 + h*64 + ig
    int b = blk >> 8;
    int h = (blk >> 6) & 3;
    int ig = blk & 63;
    int wave = threadIdx.x >> 6, lane = threadIdx.x & 63;
    int i = ig * 4 + wave;
    const float* qrow = qkv + ((long)(b * 256 + i)) * 192 + h * 16;
    float qv[16];
    #pragma unroll
    for (int d = 0; d < 16; ++d) qv[d] = qrow[d];
    float sj[4];
    #pragma unroll
    for (int q = 0; q < 4; ++q) {
        int j = lane + 64 * q;
        const float* kr = qkv + ((long)(b * 256 + j)) * 192 + 64 + h * 16;
        float s = 0.f;
        #pragma unroll
        for (int d = 0; d < 16; ++d) s += qv[d] * kr[d];
        sj[q] = s * 0.25f + biasbuf[((long)(b * 4 + h)) * LLSZ + i * 256 + j];
    }
    float mx = fmaxf(fmaxf(sj[0], sj[1]), fmaxf(sj[2], sj[3]));
    for (int k = 32; k > 0; k >>= 1) mx = fmaxf(mx, __shfl_xor(mx, k, 64));
    float wgt[4], wsum = 0.f;
    #pragma unroll
    for (int q = 0; q < 4; ++q) { wgt[q] = expf(sj[q] - mx); wsum += wgt[q]; }
    for (int k = 32; k > 0; k >>= 1) wsum += __shfl_xor(wsum, k, 64);
    float inv = 1.f / wsum;
    float o[16];
    #pragma unroll
    for (int d = 0; d < 16; ++d) o[d] = 0.f;
    #pragma unroll
    for (int q = 0; q < 4; ++q) {
        const float* vr = qkv + ((long)(b * 256 + lane + 64 * q)) * 192 + 128 + h * 16;
        #pragma unroll
        for (int d = 0; d < 16; ++d) o[d] += wgt[q] * vr[d];
    }
    #pragma unroll
    for (int d = 0; d < 16; ++d)
        for (int k = 32; k > 0; k >>= 1) o[d] += __shfl_xor(o[d], k, 64);
    if (lane == 0) {
        #pragma unroll
        for (int d = 0; d < 16; ++d)
            ctx[((long)(b * 256 + i)) * 64 + h * 16 + d] = o[d] * inv;
    }
}

// ---------- K14: seq_out = seq + ctx@W_outp + b_outp ----------
__global__ __launch_bounds__(256) void k14_seqout(
    const float* __restrict__ seq, const float* __restrict__ ctx,
    const float* __restrict__ W_outp, const float* __restrict__ b_outp,
    float* __restrict__ out)
{
    __shared__ float Wo[64 * 64];
    __shared__ float cL[4][64];
    int tid = threadIdx.x;
    #pragma unroll
    for (int k = 0; k < 16; ++k) Wo[k * 256 + tid] = W_outp[k * 256 + tid];
    int sub = tid >> 6, t = tid & 63;
    int row = blockIdx.x * 4 + sub;
    cL[sub][t] = ctx[row * 64 + t];
    __syncthreads();
    float s = b_outp[t];
    #pragma unroll
    for (int u = 0; u < 64; ++u) s += cL[sub][u] * Wo[u * 64 + t];
    out[row * 64 + t] = seq[row * 64 + t] + s;
}

extern "C" void kernel_launch(void* const* d_in, const int* in_sizes, int n_in,
                              void* d_out, int out_size, void* d_ws, size_t ws_size,
                              hipStream_t stream) {
    const float* seq_repr   = (const float*)d_in[0];
    const float* pair_repr  = (const float*)d_in[1];
    const float* g_attn     = (const float*)d_in[2];
    const float* b_attn     = (const float*)d_in[3];
    const float* g_pair     = (const float*)d_in[4];
    const float* b_pair     = (const float*)d_in[5];
    const float* W_opm_lin  = (const float*)d_in[6];
    const float* b_opm_lin  = (const float*)d_in[7];
    const float* g_opm      = (const float*)d_in[8];
    const float* b_opm      = (const float*)d_in[9];
    const float* W_opm_proj = (const float*)d_in[10];
    const float* b_opm_proj = (const float*)d_in[11];
    const float* W_exp      = (const float*)d_in[12];
    const float* W_dw       = (const float*)d_in[13];
    const float* W_se1      = (const float*)d_in[14];
    const float* b_se1      = (const float*)d_in[15];
    const float* W_se2      = (const float*)d_in[16];
    const float* b_se2      = (const float*)d_in[17];
    const float* W_pw       = (const float*)d_in[18];
    const float* W_qkv      = (const float*)d_in[19];
    const float* W_outp     = (const float*)d_in[20];
    const float* b_outp     = (const float*)d_in[21];
    const float* W_bias     = (const float*)d_in[22];

    float* out_seq  = (float*)d_out;
    float* out_pair = (float*)d_out + 32768;

    // Workspace (floats). hp aliases e1 (dead after k6); biasb aliases T (dead after k3).
    float* w = (float*)d_ws;
    float* a_buf   = w;                    // 16384
    float* am_buf  = a_buf + 16384;        // 512
    float* s2_buf  = am_buf + 512;         // 512
    float* qkv_buf = s2_buf + 512;         // 98304
    float* G_buf   = qkv_buf + 98304;      // 32768
    float* GW_buf  = G_buf + 32768;        // 32
    float* BW_buf  = GW_buf + 32;          // 32
    float* ctx     = BW_buf + 32;          // 32768
    float* st1s    = ctx + 32768;          // 128  } stats region (zeroed by kA blk0)
    float* st1q    = st1s + 128;           // 128
    float* st2s    = st1q + 128;           // 128
    float* st2q    = st2s + 128;           // 128
    float* st3s    = st2q + 128;           // 64
    float* st3q    = st3s + 64;            // 64
    float* sqs     = st3q + 64;            // 128  } total 768
    float* T_buf   = sqs + 128;            // 524288
    float* biasb   = T_buf;                // alias
    float* pair1   = T_buf + 524288;       // 4194304
    float* e1      = pair1 + 4194304;      // 8388608
    float* hp      = e1;                   // alias (4194304)
    float* h2      = e1 + 8388608;         // 8388608

    hipLaunchKernelGGL(kA, dim3(129), dim3(256), 0, stream,
                       g_opm, b_opm, W_opm_proj, b_opm_proj, G_buf, GW_buf, BW_buf,
                       st1s,
                       seq_repr, g_attn, b_attn, W_opm_lin, b_opm_lin, W_qkv,
                       a_buf, am_buf, s2_buf, qkv_buf);
    hipLaunchKernelGGL(k2_T, dim3(512), dim3(256), 0, stream, a_buf, G_buf, T_buf);
    hipLaunchKernelGGL(k3_op, dim3(4096), dim3(256), 0, stream,
                       a_buf, am_buf, s2_buf, T_buf, GW_buf, BW_buf,
                       pair_repr, pair1);
    hipLaunchKernelGGL(k4_expand, dim3(1024), dim3(256), 0, stream,
                       pair1, g_pair, b_pair, W_exp, e1);
    hipLaunchKernelGGL(k_stats, dim3(1024), dim3(256), 0, stream, e1, st1s, st1q);
    hipLaunchKernelGGL(k6_dw, dim3(4096), dim3(256), 0, stream,
                       e1, st1s, st1q, W_dw, h2, st2s, st2q);
    hipLaunchKernelGGL(k8_squeeze, dim3(1024), dim3(256), 0, stream,
                       h2, st2s, st2q, sqs);
    hipLaunchKernelGGL(k10_pw, dim3(512), dim3(256), 0, stream,
                       h2, st2s, st2q, sqs, W_se1, b_se1, W_se2, b_se2,
                       W_pw, hp);
    hipLaunchKernelGGL(k_stats, dim3(512), dim3(256), 0, stream, hp, st3s, st3q);
    hipLaunchKernelGGL(k12_merge, dim3(512), dim3(256), 0, stream,
                       pair1, hp, st3s, st3q, g_pair, b_pair, W_bias,
                       out_pair, biasb);
    hipLaunchKernelGGL(k13_attn, dim3(512), dim3(256), 0, stream,
                       qkv_buf, biasb, ctx);
    hipLaunchKernelGGL(k14_seqout, dim3(128), dim3(256), 0, stream,
                       seq_repr, ctx, W_outp, b_outp, out_seq);
}

// Round 7
// 298.847 us; speedup vs baseline: 1.1284x; 1.0033x over previous
//
#include <hip/hip_runtime.h>
#include <hip/hip_bf16.h>

#define LLSZ 65536  // L*L
#define INV_LL (1.f / 65536.f)

// B=2, L=256, SD=64, PD=32, H=4, HD=16, OH=32, EXP=64, SE=16

__device__ __forceinline__ void chan_stats(const float* sum, const float* sumsq,
                                           int chan, float& m, float& isd)
{
    m = sum[chan] * INV_LL;
    float var = sumsq[chan] * INV_LL - m * m;
    isd = rsqrtf(var + 1e-5f);
}

__device__ __forceinline__ float silu(float t) { return t / (1.f + expf(-t)); }

// ---------- kA: block 0 = {zero stats, G/GW/BW prep}; blocks 1..128 = seq LN -> a, qkv ----------
__global__ __launch_bounds__(256) void kA(
    const float* __restrict__ g_opm, const float* __restrict__ b_opm,
    const float* __restrict__ Wproj, const float* __restrict__ b_proj,
    float* __restrict__ G, float* __restrict__ GW, float* __restrict__ BW,
    float* __restrict__ stats0,   // 768 floats to zero
    const float* __restrict__ seq, const float* __restrict__ g_attn,
    const float* __restrict__ b_attn, const float* __restrict__ W_lin,
    const float* __restrict__ b_lin, const float* __restrict__ W_qkv,
    float* __restrict__ a, float* __restrict__ am, float* __restrict__ s2,
    float* __restrict__ qkv)
{
    int tid = threadIdx.x;
    if (blockIdx.x == 0) {
        for (int k = tid; k < 768; k += 256) stats0[k] = 0.f;
        int p = tid & 31, rg = tid >> 5;  // rg 0..7
        float gw = 0.f, bw = 0.f;
        #pragma unroll 8
        for (int k = 0; k < 128; ++k) {
            int de = k * 8 + rg;
            float wv = Wproj[de * 32 + p];
            float gv = g_opm[de] * wv;
            G[de * 32 + p] = gv;
            gw += gv;
            bw += b_opm[de] * wv;
        }
        __shared__ float rG[256], rB[256];
        rG[rg * 32 + p] = gw;
        rB[rg * 32 + p] = bw;
        __syncthreads();
        for (int s = 4; s > 0; s >>= 1) {
            if (rg < s) {
                rG[rg * 32 + p] += rG[(rg + s) * 32 + p];
                rB[rg * 32 + p] += rB[(rg + s) * 32 + p];
            }
            __syncthreads();
        }
        if (tid < 32) { GW[p] = rG[p]; BW[p] = rB[p] + b_proj[p]; }
    } else {
        __shared__ float Wq[64 * 192];
        __shared__ float Wl[64 * 32];
        __shared__ float xL[4][64];
        #pragma unroll
        for (int k = 0; k < 48; ++k) Wq[k * 256 + tid] = W_qkv[k * 256 + tid];
        #pragma unroll
        for (int k = 0; k < 8; ++k) Wl[k * 256 + tid] = W_lin[k * 256 + tid];
        int sub = tid >> 6, t = tid & 63;
        int row = (blockIdx.x - 1) * 4 + sub;
        float v = seq[row * 64 + t];
        float m = v;
        for (int k = 32; k > 0; k >>= 1) m += __shfl_xor(m, k, 64);
        m *= (1.f / 64.f);
        float d = v - m;
        float var = d * d;
        for (int k = 32; k > 0; k >>= 1) var += __shfl_xor(var, k, 64);
        var *= (1.f / 64.f);
        float x = d * rsqrtf(var + 1e-5f) * g_attn[t] + b_attn[t];
        xL[sub][t] = x;
        __syncthreads();
        if (t < 32) {
            float s = 0.f;
            #pragma unroll
            for (int dd = 0; dd < 64; ++dd) s += xL[sub][dd] * Wl[dd * 32 + t];
            s += b_lin[t];
            a[row * 32 + t] = s;
            float mm = s, ss = s * s;
            for (int k = 16; k > 0; k >>= 1) {
                mm += __shfl_xor(mm, k, 32);
                ss += __shfl_xor(ss, k, 32);
            }
            if (t == 0) { am[row] = mm * (1.f / 32.f); s2[row] = ss * (1.f / 32.f); }
        }
        #pragma unroll
        for (int c3 = 0; c3 < 3; ++c3) {
            int c = c3 * 64 + t;
            float s = 0.f;
            #pragma unroll
            for (int dd = 0; dd < 64; ++dd) s += xL[sub][dd] * Wq[dd * 192 + c];
            qkv[row * 192 + c] = s;
        }
    }
}

// ---------- K2: T[row, e*32+p] = sum_d a[row,d]*G[d*1024+e*32+p] ----------
__global__ __launch_bounds__(256) void k2_T(
    const float* __restrict__ a, const float* __restrict__ G, float* __restrict__ T)
{
    int row = blockIdx.x;
    int tid = threadIdx.x;
    __shared__ float aL[32];
    if (tid < 32) aL[tid] = a[row * 32 + tid];
    __syncthreads();
    for (int k = 0; k < 4; ++k) {
        int idx = k * 256 + tid;
        float s = 0.f;
        #pragma unroll
        for (int d = 0; d < 32; ++d) s += aL[d] * G[d * 1024 + idx];
        T[row * 1024 + idx] = s;
    }
}

// ---------- K3: pair1 = pair_repr + op ----------
__global__ __launch_bounds__(256) void k3_op(
    const float* __restrict__ a, const float* __restrict__ am,
    const float* __restrict__ s2, const float* __restrict__ T,
    const float* __restrict__ GW, const float* __restrict__ BW,
    const float* __restrict__ pair_in, float* __restrict__ pair1)
{
    int blk = blockIdx.x;           // row*8 + jg
    int row = blk >> 3;             // b*256 + i
    int jg = blk & 7;
    int b = row >> 8;
    int j0 = jg * 32;
    int tid = threadIdx.x;
    __shared__ float Tl[1024];
    __shared__ float aL[32 * 33];
    __shared__ float amL[32], s2L[32], gwL[32], bwL[32];
    ((float4*)Tl)[tid] = ((const float4*)(T + (long)row * 1024))[tid];
    for (int k = 0; k < 4; ++k) {
        int idx = k * 256 + tid;
        aL[(idx >> 5) * 33 + (idx & 31)] = a[(b * 256 + j0) * 32 + idx];
    }
    if (tid < 32) {
        amL[tid] = am[b * 256 + j0 + tid];
        s2L[tid] = s2[b * 256 + j0 + tid];
        gwL[tid] = GW[tid];
        bwL[tid] = BW[tid];
    }
    __syncthreads();
    int jl = tid >> 3, cq = tid & 7;
    float am_i = am[row], s2_i = s2[row];
    float m = am_i * amL[jl];
    float isd = rsqrtf(s2_i * s2L[jl] - m * m + 1e-5f);
    long base = ((long)row * 256 + j0 + jl) * 32 + cq * 4;
    float4 pv = *(const float4*)(pair_in + base);
    float o[4];
    #pragma unroll
    for (int u = 0; u < 4; ++u) {
        int p = cq * 4 + u;
        float S = 0.f;
        #pragma unroll
        for (int e = 0; e < 32; ++e) S += aL[jl * 33 + e] * Tl[e * 32 + p];
        o[u] = isd * (S - m * gwL[p]) + bwL[p];
    }
    pv.x += o[0]; pv.y += o[1]; pv.z += o[2]; pv.w += o[3];
    *(float4*)(pair1 + base) = pv;
}

// ---------- K4: thread-per-pixel. LN(pair1) in-thread; e1 = pn @ W_exp^T (s_load weights) ----------
__global__ __launch_bounds__(256) void k4_expand(
    const float* __restrict__ pair1, const float* __restrict__ g_pair,
    const float* __restrict__ b_pair, const float* __restrict__ W_exp,
    float* __restrict__ e1)
{
    int b = blockIdx.x >> 9;
    int oh = (blockIdx.x >> 8) & 1;
    int px = (blockIdx.x & 255) * 256 + threadIdx.x;
    long pixel = (long)b * LLSZ + px;
    float x[32];
    const float4* src = (const float4*)(pair1 + pixel * 32);
    #pragma unroll
    for (int k = 0; k < 8; ++k) {
        float4 v = src[k];
        x[k * 4 + 0] = v.x; x[k * 4 + 1] = v.y;
        x[k * 4 + 2] = v.z; x[k * 4 + 3] = v.w;
    }
    float s = 0.f, q = 0.f;
    #pragma unroll
    for (int c = 0; c < 32; ++c) { s += x[c]; q += x[c] * x[c]; }
    float mu = s * (1.f / 32.f);
    float isd = rsqrtf(q * (1.f / 32.f) - mu * mu + 1e-5f);
    #pragma unroll
    for (int c = 0; c < 32; ++c)
        x[c] = (x[c] - mu) * isd * g_pair[c] + b_pair[c];   // uniform s_load
    float* dst = e1 + ((long)(b * 64 + oh * 32)) * LLSZ + px;
    #pragma unroll
    for (int oo = 0; oo < 32; ++oo) {
        int o = oh * 32 + oo;
        float acc = 0.f;
        #pragma unroll
        for (int c = 0; c < 32; ++c) acc += x[c] * W_exp[o * 32 + c];  // s_load
        dst[(long)oo * LLSZ] = acc;
    }
}

// ---------- stats: per-channel sum/sumsq, 8 segments + atomics (pre-zeroed) ----------
__global__ __launch_bounds__(256) void k_stats(
    const float* __restrict__ buf, float* __restrict__ sum, float* __restrict__ sumsq)
{
    int bid = blockIdx.x;
    int chan = bid >> 3, seg = bid & 7;
    int tid = threadIdx.x;
    const float4* p = (const float4*)(buf + (long)chan * LLSZ + seg * 8192);
    float s = 0.f, ss = 0.f;
    #pragma unroll
    for (int k = 0; k < 8; ++k) {
        float4 v = p[k * 256 + tid];
        s += v.x + v.y + v.z + v.w;
        ss += v.x * v.x + v.y * v.y + v.z * v.z + v.w * v.w;
    }
    for (int k = 32; k > 0; k >>= 1) { s += __shfl_xor(s, k, 64); ss += __shfl_xor(ss, k, 64); }
    __shared__ float rs[4], rq[4];
    int wave = tid >> 6;
    if ((tid & 63) == 0) { rs[wave] = s; rq[wave] = ss; }
    __syncthreads();
    if (tid == 0) {
        atomicAdd(&sum[chan], rs[0] + rs[1] + rs[2] + rs[3]);
        atomicAdd(&sumsq[chan], rq[0] + rq[1] + rq[2] + rq[3]);
    }
}

// ---------- K6: depthwise 3x3 on silu(inorm(e1)) -> h2; fused stats2 ----------
__global__ __launch_bounds__(256) void k6_dw(
    const float* __restrict__ e1, const float* __restrict__ st1s,
    const float* __restrict__ st1q, const float* __restrict__ W_dw,
    float* __restrict__ h2, float* __restrict__ st2s, float* __restrict__ st2q)
{
    int blk = blockIdx.x;            // chan*32 + rg
    int chan = blk >> 5;             // 0..127
    int r0 = (blk & 31) * 8;
    int o = chan & 63;
    int tid = threadIdx.x;
    float m, isd;
    chan_stats(st1s, st1q, chan, m, isd);
    __shared__ float sL[10][258];
    const float* src = e1 + (long)chan * LLSZ;
    for (int k = tid; k < 640; k += 256) {   // 10 rows x 64 float4
        int rr = k >> 6, c4 = k & 63;
        int g = r0 - 1 + rr;
        float4 v = make_float4(0.f, 0.f, 0.f, 0.f);
        bool ok = (g >= 0 && g < 256);
        if (ok) v = *(const float4*)(src + g * 256 + c4 * 4);
        float t;
        t = (v.x - m) * isd; v.x = ok ? silu(t) : 0.f;
        t = (v.y - m) * isd; v.y = ok ? silu(t) : 0.f;
        t = (v.z - m) * isd; v.z = ok ? silu(t) : 0.f;
        t = (v.w - m) * isd; v.w = ok ? silu(t) : 0.f;
        sL[rr][1 + c4 * 4 + 0] = v.x;
        sL[rr][1 + c4 * 4 + 1] = v.y;
        sL[rr][1 + c4 * 4 + 2] = v.z;
        sL[rr][1 + c4 * 4 + 3] = v.w;
    }
    if (tid < 10) { sL[tid][0] = 0.f; sL[tid][257] = 0.f; }
    float w[9];
    #pragma unroll
    for (int k = 0; k < 9; ++k) w[k] = W_dw[o * 9 + k];
    __syncthreads();
    int c = tid;
    float bs = 0.f, bq = 0.f;
    #pragma unroll
    for (int rr = 0; rr < 8; ++rr) {
        float s = 0.f;
        #pragma unroll
        for (int ki = 0; ki < 3; ++ki)
            #pragma unroll
            for (int kj = 0; kj < 3; ++kj)
                s += sL[rr + ki][c + kj] * w[ki * 3 + kj];
        h2[(long)chan * LLSZ + (r0 + rr) * 256 + c] = s;
        bs += s; bq += s * s;
    }
    for (int k = 32; k > 0; k >>= 1) { bs += __shfl_xor(bs, k, 64); bq += __shfl_xor(bq, k, 64); }
    __shared__ float r2s[4], r2q[4];
    int wave = tid >> 6;
    if ((tid & 63) == 0) { r2s[wave] = bs; r2q[wave] = bq; }
    __syncthreads();
    if (tid == 0) {
        atomicAdd(&st2s[chan], r2s[0] + r2s[1] + r2s[2] + r2s[3]);
        atomicAdd(&st2q[chan], r2q[0] + r2q[1] + r2q[2] + r2q[3]);
    }
}

// ---------- K8: squeeze-sum of silu(inorm(h2)) ----------
__global__ __launch_bounds__(256) void k8_squeeze(
    const float* __restrict__ h2, const float* __restrict__ st2s,
    const float* __restrict__ st2q, float* __restrict__ sqs)
{
    int bid = blockIdx.x;
    int chan = bid >> 3, seg = bid & 7;
    int tid = threadIdx.x;
    float m, isd;
    chan_stats(st2s, st2q, chan, m, isd);
    const float4* p = (const float4*)(h2 + (long)chan * LLSZ + seg * 8192);
    float s = 0.f;
    #pragma unroll
    for (int k = 0; k < 8; ++k) {
        float4 v = p[k * 256 + tid];
        s += silu((v.x - m) * isd) + silu((v.y - m) * isd)
           + silu((v.z - m) * isd) + silu((v.w - m) * isd);
    }
    for (int k = 32; k > 0; k >>= 1) s += __shfl_xor(s, k, 64);
    __shared__ float rs[4];
    int wave = tid >> 6;
    if ((tid & 63) == 0) rs[wave] = s;
    __syncthreads();
    if (tid == 0) atomicAdd(&sqs[chan], rs[0] + rs[1] + rs[2] + rs[3]);
}

// ---------- K10: thread-per-pixel pointwise conv; 64 batched loads, s_load weights ----------
__global__ __launch_bounds__(256) void k10_pw(
    const float* __restrict__ h2, const float* __restrict__ st2s,
    const float* __restrict__ st2q, const float* __restrict__ sqs,
    const float* __restrict__ W_se1, const float* __restrict__ b_se1,
    const float* __restrict__ W_se2, const float* __restrict__ b_se2,
    const float* __restrict__ W_pw, float* __restrict__ hp)
{
    int b = blockIdx.x >> 8;
    int px = (blockIdx.x & 255) * 256 + threadIdx.x;
    int tid = threadIdx.x;
    __shared__ float s1L[16];
    __shared__ float sqvL[64];
    if (tid < 16) {
        float s = 0.f;
        for (int c = 0; c < 64; ++c) s += sqs[b * 64 + c] * W_se1[tid * 64 + c];
        s = s * INV_LL + b_se1[tid];
        s1L[tid] = silu(s);
    }
    __syncthreads();
    if (tid < 64) {
        float s = 0.f;
        #pragma unroll
        for (int j = 0; j < 16; ++j) s += s1L[j] * W_se2[tid * 16 + j];
        s += b_se2[tid];
        sqvL[tid] = 1.f / (1.f + expf(-s));
    }
    __syncthreads();
    // ---- batched loads: all 64 channel values in flight before any compute ----
    float v[64];
    const float* src = h2 + ((long)b * 64) * LLSZ + px;
    #pragma unroll
    for (int c = 0; c < 64; ++c) v[c] = src[(long)c * LLSZ];
    __builtin_amdgcn_sched_barrier(0);
    float acc[32];
    #pragma unroll
    for (int p = 0; p < 32; ++p) acc[p] = 0.f;
    #pragma unroll
    for (int c = 0; c < 64; ++c) {
        float m, isd;
        chan_stats(st2s, st2q, b * 64 + c, m, isd);   // uniform s_load
        float x = silu((v[c] - m) * isd) * sqvL[c];
        #pragma unroll
        for (int p = 0; p < 32; ++p) acc[p] += x * W_pw[p * 64 + c];  // s_load
    }
    float* dst = hp + ((long)b * 32) * LLSZ + px;
    #pragma unroll
    for (int p = 0; p < 32; ++p) dst[(long)p * LLSZ] = acc[p];
}

// ---------- K12: thread-per-pixel merge; batched loads ----------
__global__ __launch_bounds__(256) void k12_merge(
    const float* __restrict__ pair1, const float* __restrict__ hp,
    const float* __restrict__ st3s, const float* __restrict__ st3q,
    const float* __restrict__ g_pair, const float* __restrict__ b_pair,
    const float* __restrict__ W_bias, float* __restrict__ pair_out,
    float* __restrict__ biasbuf)
{
    int b = blockIdx.x >> 8;
    int px = (blockIdx.x & 255) * 256 + threadIdx.x;
    long pixel = (long)b * LLSZ + px;
    // ---- batched loads ----
    float4 r[8];
    const float4* src = (const float4*)(pair1 + pixel * 32);
    #pragma unroll
    for (int k = 0; k < 8; ++k) r[k] = src[k];
    float hv[32];
    const float* hpb = hp + ((long)b * 32) * LLSZ + px;
    #pragma unroll
    for (int p = 0; p < 32; ++p) hv[p] = hpb[(long)p * LLSZ];
    __builtin_amdgcn_sched_barrier(0);
    float v1[32];
    #pragma unroll
    for (int k = 0; k < 8; ++k) {
        v1[k * 4 + 0] = r[k].x; v1[k * 4 + 1] = r[k].y;
        v1[k * 4 + 2] = r[k].z; v1[k * 4 + 3] = r[k].w;
    }
    float s = 0.f, q = 0.f;
    #pragma unroll
    for (int c = 0; c < 32; ++c) { s += v1[c]; q += v1[c] * v1[c]; }
    float mu = s * (1.f / 32.f);
    float isd = rsqrtf(q * (1.f / 32.f) - mu * mu + 1e-5f);
    float vo[32];
    #pragma unroll
    for (int p = 0; p < 32; ++p) {
        float m3, isd3;
        chan_stats(st3s, st3q, b * 32 + p, m3, isd3);  // uniform s_load
        float pnv = (v1[p] - mu) * isd * g_pair[p] + b_pair[p];
        vo[p] = v1[p] + pnv + (hv[p] - m3) * isd3;
    }
    float4* dst = (float4*)(pair_out + pixel * 32);
    #pragma unroll
    for (int k = 0; k < 8; ++k)
        dst[k] = make_float4(vo[k * 4], vo[k * 4 + 1], vo[k * 4 + 2], vo[k * 4 + 3]);
    float s2_ = 0.f, q2 = 0.f;
    #pragma unroll
    for (int c = 0; c < 32; ++c) { s2_ += vo[c]; q2 += vo[c] * vo[c]; }
    float mu2 = s2_ * (1.f / 32.f);
    float isd2 = rsqrtf(q2 * (1.f / 32.f) - mu2 * mu2 + 1e-5f);
    float t[4] = {0.f, 0.f, 0.f, 0.f};
    #pragma unroll
    for (int p = 0; p < 32; ++p) {
        float pn2 = (vo[p] - mu2) * isd2 * g_pair[p] + b_pair[p];
        #pragma unroll
        for (int h = 0; h < 4; ++h) t[h] += pn2 * W_bias[p * 4 + h];  // s_load
    }
    #pragma unroll
    for (int h = 0; h < 4; ++h)
        biasbuf[((long)(b * 4 + h)) * LLSZ + px] = t[h];
}

// ---------- K13: attention; K/V staged in LDS once per block (shared by 4 waves) ----------
__global__ __launch_bounds__(256) void k13_attn(
    const float* __restrict__ qkv, const float* __restrict__ biasbuf,
    float* __restrict__ ctx)
{
    int blk = blockIdx.x;           // b*256 + h*64 + ig
    int b = blk >> 8;
    int h = (blk >> 6) & 3;
    int ig = blk & 63;
    int tid = threadIdx.x;
    int wave = tid >> 6, lane = tid & 63;
    __shared__ float kL[16][256];
    __shared__ float vL[16][256];
    {   // stage K and V rows for this (b,h): thread tid owns row j = tid
        const float4* kr = (const float4*)(qkv + ((long)(b * 256 + tid)) * 192 + 64 + h * 16);
        float4 k0 = kr[0], k1 = kr[1], k2 = kr[2], k3 = kr[3];
        const float4* vr = (const float4*)(qkv + ((long)(b * 256 + tid)) * 192 + 128 + h * 16);
        float4 w0 = vr[0], w1 = vr[1], w2 = vr[2], w3 = vr[3];
        kL[ 0][tid] = k0.x; kL[ 1][tid] = k0.y; kL[ 2][tid] = k0.z; kL[ 3][tid] = k0.w;
        kL[ 4][tid] = k1.x; kL[ 5][tid] = k1.y; kL[ 6][tid] = k1.z; kL[ 7][tid] = k1.w;
        kL[ 8][tid] = k2.x; kL[ 9][tid] = k2.y; kL[10][tid] = k2.z; kL[11][tid] = k2.w;
        kL[12][tid] = k3.x; kL[13][tid] = k3.y; kL[14][tid] = k3.z; kL[15][tid] = k3.w;
        vL[ 0][tid] = w0.x; vL[ 1][tid] = w0.y; vL[ 2][tid] = w0.z; vL[ 3][tid] = w0.w;
        vL[ 4][tid] = w1.x; vL[ 5][tid] = w1.y; vL[ 6][tid] = w1.z; vL[ 7][tid] = w1.w;
        vL[ 8][tid] = w2.x; vL[ 9][tid] = w2.y; vL[10][tid] = w2.z; vL[11][tid] = w2.w;
        vL[12][tid] = w3.x; vL[13][tid] = w3.y; vL[14][tid] = w3.z; vL[15][tid] = w3.w;
    }
    __syncthreads();
    int i = ig * 4 + wave;
    const float* qrow = qkv + ((long)(b * 256 + i)) * 192 + h * 16;
    float qv[16];
    #pragma unroll
    for (int d = 0; d < 16; ++d) qv[d] = qrow[d];
    float sj[4];
    #pragma unroll
    for (int q = 0; q < 4; ++q) {
        int j = 64 * q + lane;
        float s = 0.f;
        #pragma unroll
        for (int d = 0; d < 16; ++d) s += qv[d] * kL[d][j];
        sj[q] = s * 0.25f + biasbuf[((long)(b * 4 + h)) * LLSZ + i * 256 + j];
    }
    float mx = fmaxf(fmaxf(sj[0], sj[1]), fmaxf(sj[2], sj[3]));
    for (int k = 32; k > 0; k >>= 1) mx = fmaxf(mx, __shfl_xor(mx, k, 64));
    float wgt[4], wsum = 0.f;
    #pragma unroll
    for (int q = 0; q < 4; ++q) { wgt[q] = expf(sj[q] - mx); wsum += wgt[q]; }
    for (int k = 32; k > 0; k >>= 1) wsum += __shfl_xor(wsum, k, 64);
    float inv = 1.f / wsum;
    float o[16];
    #pragma unroll
    for (int d = 0; d < 16; ++d) o[d] = 0.f;
    #pragma unroll
    for (int q = 0; q < 4; ++q) {
        int j = 64 * q + lane;
        #pragma unroll
        for (int d = 0; d < 16; ++d) o[d] += wgt[q] * vL[d][j];
    }
    #pragma unroll
    for (int d = 0; d < 16; ++d)
        for (int k = 32; k > 0; k >>= 1) o[d] += __shfl_xor(o[d], k, 64);
    if (lane == 0) {
        #pragma unroll
        for (int d = 0; d < 16; ++d)
            ctx[((long)(b * 256 + i)) * 64 + h * 16 + d] = o[d] * inv;
    }
}

// ---------- K14: seq_out = seq + ctx@W_outp + b_outp ----------
__global__ __launch_bounds__(256) void k14_seqout(
    const float* __restrict__ seq, const float* __restrict__ ctx,
    const float* __restrict__ W_outp, const float* __restrict__ b_outp,
    float* __restrict__ out)
{
    __shared__ float Wo[64 * 64];
    __shared__ float cL[4][64];
    int tid = threadIdx.x;
    #pragma unroll
    for (int k = 0; k < 16; ++k) Wo[k * 256 + tid] = W_outp[k * 256 + tid];
    int sub = tid >> 6, t = tid & 63;
    int row = blockIdx.x * 4 + sub;
    cL[sub][t] = ctx[row * 64 + t];
    __syncthreads();
    float s = b_outp[t];
    #pragma unroll
    for (int u = 0; u < 64; ++u) s += cL[sub][u] * Wo[u * 64 + t];
    out[row * 64 + t] = seq[row * 64 + t] + s;
}

extern "C" void kernel_launch(void* const* d_in, const int* in_sizes, int n_in,
                              void* d_out, int out_size, void* d_ws, size_t ws_size,
                              hipStream_t stream) {
    const float* seq_repr   = (const float*)d_in[0];
    const float* pair_repr  = (const float*)d_in[1];
    const float* g_attn     = (const float*)d_in[2];
    const float* b_attn     = (const float*)d_in[3];
    const float* g_pair     = (const float*)d_in[4];
    const float* b_pair     = (const float*)d_in[5];
    const float* W_opm_lin  = (const float*)d_in[6];
    const float* b_opm_lin  = (const float*)d_in[7];
    const float* g_opm      = (const float*)d_in[8];
    const float* b_opm      = (const float*)d_in[9];
    const float* W_opm_proj = (const float*)d_in[10];
    const float* b_opm_proj = (const float*)d_in[11];
    const float* W_exp      = (const float*)d_in[12];
    const float* W_dw       = (const float*)d_in[13];
    const float* W_se1      = (const float*)d_in[14];
    const float* b_se1      = (const float*)d_in[15];
    const float* W_se2      = (const float*)d_in[16];
    const float* b_se2      = (const float*)d_in[17];
    const float* W_pw       = (const float*)d_in[18];
    const float* W_qkv      = (const float*)d_in[19];
    const float* W_outp     = (const float*)d_in[20];
    const float* b_outp     = (const float*)d_in[21];
    const float* W_bias     = (const float*)d_in[22];

    float* out_seq  = (float*)d_out;
    float* out_pair = (float*)d_out + 32768;

    // Workspace (floats). hp aliases e1 (dead after k6); biasb aliases T (dead after k3).
    float* w = (float*)d_ws;
    float* a_buf   = w;                    // 16384
    float* am_buf  = a_buf + 16384;        // 512
    float* s2_buf  = am_buf + 512;         // 512
    float* qkv_buf = s2_buf + 512;         // 98304
    float* G_buf   = qkv_buf + 98304;      // 32768
    float* GW_buf  = G_buf + 32768;        // 32
    float* BW_buf  = GW_buf + 32;          // 32
    float* ctx     = BW_buf + 32;          // 32768
    float* st1s    = ctx + 32768;          // 128  } stats region (zeroed by kA blk0)
    float* st1q    = st1s + 128;           // 128
    float* st2s    = st1q + 128;           // 128
    float* st2q    = st2s + 128;           // 128
    float* st3s    = st2q + 128;           // 64
    float* st3q    = st3s + 64;            // 64
    float* sqs     = st3q + 64;            // 128  } total 768
    float* T_buf   = sqs + 128;            // 524288
    float* biasb   = T_buf;                // alias
    float* pair1   = T_buf + 524288;       // 4194304
    float* e1      = pair1 + 4194304;      // 8388608
    float* hp      = e1;                   // alias (4194304)
    float* h2      = e1 + 8388608;         // 8388608

    hipLaunchKernelGGL(kA, dim3(129), dim3(256), 0, stream,
                       g_opm, b_opm, W_opm_proj, b_opm_proj, G_buf, GW_buf, BW_buf,
                       st1s,
                       seq_repr, g_attn, b_attn, W_opm_lin, b_opm_lin, W_qkv,
                       a_buf, am_buf, s2_buf, qkv_buf);
    hipLaunchKernelGGL(k2_T, dim3(512), dim3(256), 0, stream, a_buf, G_buf, T_buf);
    hipLaunchKernelGGL(k3_op, dim3(4096), dim3(256), 0, stream,
                       a_buf, am_buf, s2_buf, T_buf, GW_buf, BW_buf,
                       pair_repr, pair1);
    hipLaunchKernelGGL(k4_expand, dim3(1024), dim3(256), 0, stream,
                       pair1, g_pair, b_pair, W_exp, e1);
    hipLaunchKernelGGL(k_stats, dim3(1024), dim3(256), 0, stream, e1, st1s, st1q);
    hipLaunchKernelGGL(k6_dw, dim3(4096), dim3(256), 0, stream,
                       e1, st1s, st1q, W_dw, h2, st2s, st2q);
    hipLaunchKernelGGL(k8_squeeze, dim3(1024), dim3(256), 0, stream,
                       h2, st2s, st2q, sqs);
    hipLaunchKernelGGL(k10_pw, dim3(512), dim3(256), 0, stream,
                       h2, st2s, st2q, sqs, W_se1, b_se1, W_se2, b_se2,
                       W_pw, hp);
    hipLaunchKernelGGL(k_stats, dim3(512), dim3(256), 0, stream, hp, st3s, st3q);
    hipLaunchKernelGGL(k12_merge, dim3(512), dim3(256), 0, stream,
                       pair1, hp, st3s, st3q, g_pair, b_pair, W_bias,
                       out_pair, biasb);
    hipLaunchKernelGGL(k13_attn, dim3(512), dim3(256), 0, stream,
                       qkv_buf, biasb, ctx);
    hipLaunchKernelGGL(k14_seqout, dim3(128), dim3(256), 0, stream,
                       seq_repr, ctx, W_outp, b_outp, out_seq);
}